// Round 1
// baseline (211.291 us; speedup 1.0000x reference)
//
#include <hip/hip_runtime.h>

// TwoDigitAdditionNetwork SNN — fused single-block simulation.
// Structure: spk_in nonzero only at t=0 -> hidden spikes only at step 0 ->
// output drive only at step 1 -> (with this input) all outputs fire at t=1
// and `done` freezes everything. So the kernel is one input scatter, one
// hidden->output scatter, and a handful of element-wise sweeps.

#define HIDDEN   16384
#define IN_SIZE  40
#define OUT_SIZE 22
#define FAN0     8192   // HIDDEN/2
#define FAN1     11     // OUT_SIZE/2
#define NT       1024   // threads per block (16 waves)
#define PT       (HIDDEN / NT)   // 16 hidden neurons per thread
#define NW       (NT / 64)       // 16 waves
#define ACC_STRIDE 33            // per-wave out-accumulator stride (bank rotate)

__global__ __launch_bounds__(NT, 1)
void snn_fused_kernel(const float* __restrict__ in_spk,
                      const float* __restrict__ w0,
                      const int*   __restrict__ tgt0,
                      const float* __restrict__ w1,
                      const int*   __restrict__ tgt1,
                      const int*   __restrict__ mt,
                      float*       __restrict__ out)
{
    __shared__ float S[HIDDEN];        // 64 KiB exactly; reused twice (see below)
    const int tid = threadIdx.x;
    const float decay = 0.9512294245007140f;   // exp(-1/20)

    // max_timesteps: robust to int32 or float32 single-element storage.
    int T = mt[0];
    if (T < 0 || T > 1000000) {
        float tf = __int_as_float(T);
        T = (tf > 0.0f && tf < 1.0e6f) ? (int)tf : 0;
    }

    // ---- prologue: t=0 input scatter (add_h) into S ----
    #pragma unroll
    for (int i = 0; i < PT; ++i) S[i * NT + tid] = 0.0f;
    __syncthreads();

    for (int r = 0; r < IN_SIZE; ++r) {
        float s = in_spk[r];                 // spk_in = input_spikes * 2
        if (s != 0.0f) {
            float sv = 2.0f * s;
            const float* wr = w0   + (size_t)r * FAN0;
            const int*   tr = tgt0 + (size_t)r * FAN0;
            for (int e = tid; e < FAN0; e += NT)
                atomicAdd(&S[tr[e]], sv * wr[e]);
        }
    }
    __syncthreads();

    float pot[PT];
    #pragma unroll
    for (int i = 0; i < PT; ++i) pot[i] = S[i * NT + tid];
    __syncthreads();   // all reads of scatter buffer complete

    // ---- overlay control region on S (scatter buffer is dead now) ----
    float* acc   = S;                      // [NW][ACC_STRIDE] = 528 floats
    float* pot_o = S + 560;                // 22
    float* outt  = S + 582;                // 22 (first-spike times, as float)
    int*   ctrl  = (int*)(S + 604);        // [0]=fired bitmask, [1]=done

    if (tid < NW * ACC_STRIDE) acc[tid] = 0.0f;
    if (tid < OUT_SIZE) { pot_o[tid] = 0.0f; outt[tid] = -1.0f; }
    if (tid == 0) { ctrl[0] = 0; ctrl[1] = 0; }
    __syncthreads();

    unsigned spk = 0u;                     // this thread's 16 hidden spike flags
    float* macc = acc + (tid >> 6) * ACC_STRIDE;   // my wave's accumulator

    for (int t = 0; t < T; ++t) {
        // phase A: scatter previous step's hidden spikes into output accs
        if (spk) {
            #pragma unroll
            for (int i = 0; i < PT; ++i) {
                if ((spk >> i) & 1u) {
                    const int h = i * NT + tid;
                    const float* wr = w1   + (size_t)h * FAN1;
                    const int*   tr = tgt1 + (size_t)h * FAN1;
                    for (int k = 0; k < FAN1; ++k)
                        atomicAdd(&macc[tr[k]], wr[k]);
                }
            }
        }
        __syncthreads();

        // phase B: hidden decay / spike / reset (registers only)
        unsigned ns = 0u;
        #pragma unroll
        for (int i = 0; i < PT; ++i) {
            float p = pot[i] * decay;      // (pot + add) * decay; add folded in at t=0
            bool sp = (p >= 0.3f);
            pot[i] = sp ? 0.0f : p;
            ns |= (sp ? (1u << i) : 0u);
        }
        spk = ns;

        // outputs: 22 threads reduce the per-wave accs and update state
        if (tid < OUT_SIZE) {
            float a = 0.0f;
            #pragma unroll
            for (int w = 0; w < NW; ++w) {
                a += acc[w * ACC_STRIDE + tid];
                acc[w * ACC_STRIDE + tid] = 0.0f;   // ready for next step
            }
            float po = (pot_o[tid] + a) * decay;
            pot_o[tid] = po;
            bool ab = (po >= 0.3f);
            if (ab) {
                unsigned fm = (unsigned)ctrl[0];    // only my own bit matters
                if (!((fm >> tid) & 1u)) outt[tid] = (float)t;  // latch first spike
                atomicOr(&ctrl[0], 1 << tid);
            }
        }
        __syncthreads();
        if (tid == 0 && ctrl[0] == 0x3FFFFF) ctrl[1] = 1;  // all 22 fired -> done
        __syncthreads();
        if (ctrl[1]) break;    // reference freezes state once done; breaking == freezing
    }

    if (T <= 0) {              // scan over empty range returns the zero init
        #pragma unroll
        for (int i = 0; i < PT; ++i) pot[i] = 0.0f;
    }

    // ---- epilogue: d_out = [out_t(22) | pot_o(22) | pot_h(16384)] as f32 ----
    if (tid < OUT_SIZE) {
        out[tid]            = outt[tid];
        out[OUT_SIZE + tid] = pot_o[tid];
    }
    #pragma unroll
    for (int i = 0; i < PT; ++i)
        out[2 * OUT_SIZE + i * NT + tid] = pot[i];
}

extern "C" void kernel_launch(void* const* d_in, const int* in_sizes, int n_in,
                              void* d_out, int out_size, void* d_ws, size_t ws_size,
                              hipStream_t stream) {
    const float* in_spk = (const float*)d_in[0];   // (40,)
    const float* w0     = (const float*)d_in[1];   // (40, 8192)
    const int*   tgt0   = (const int*)  d_in[2];   // (40, 8192)
    const float* w1     = (const float*)d_in[3];   // (16384, 11)
    const int*   tgt1   = (const int*)  d_in[4];   // (16384, 11)
    const int*   mt     = (const int*)  d_in[5];   // scalar max_timesteps
    float*       out    = (float*)d_out;           // 22 + 22 + 16384 = 16428 f32

    snn_fused_kernel<<<1, NT, 0, stream>>>(in_spk, w0, tgt0, w1, tgt1, mt, out);
}

// Round 2
// 77.176 us; speedup vs baseline: 2.7378x; 2.7378x over previous
//
#include <hip/hip_runtime.h>

// TwoDigitAdditionNetwork SNN — closed-form, multi-kernel, whole-GPU version.
//
// Key fact: spk_in != 0 only at t=0  =>  hidden spikes only at step 0  =>
// output drive only at step 1  =>  after step 1 all state evolves by pure
// decay (or is frozen by `done`). Closed form:
//   ph0 = add_h*d ; s_h = ph0>=.3 ; ph0' = s_h?0:ph0
//   fired = add_o*d >= .3 (step 1) ; out_t = fired?1:-1           (T>=2)
//   t_eff = (T<=0: n/a) (T==1: 0) (allfired: 1) (else: T-1)
//   pot_h = ph0' * d^t_eff ; pot_o = add_o * d^t_eff (T>=2, else 0)
//
// Pipeline (stream-ordered, graph-capture safe):
//   memset(ws)  ->  K1 input scatter (global atomics, 1280 blocks)
//   ->  K2 hidden update + hierarchical output scatter (64 blocks)
//   ->  K3 output finalize, compute g = d^t_eff into ws (1 wave)
//   ->  K4 scale pot_h by g (64 blocks)

#define HIDDEN   16384
#define IN_SIZE  40
#define OUT_SIZE 22
#define FAN0     8192
#define FAN1     11
#define DECAY    0.9512294245007140f   // exp(-1/20)
#define THRESH   0.3f

// ws layout (floats): [0..16383] add_h acc | [16384..16405] add_o acc | [16406] g

__global__ void k1_input_scatter(const float* __restrict__ in_spk,
                                 const float* __restrict__ w0,
                                 const int*   __restrict__ tgt0,
                                 float*       __restrict__ acc_h)
{
    const int row = blockIdx.y;
    float s = in_spk[row];
    if (s == 0.0f) return;                       // ~36/40 rows idle
    const float sv = 2.0f * s;                   // spk_in = input_spikes * 2
    const int e = blockIdx.x * blockDim.x + threadIdx.x;   // 0..8191
    const size_t idx = (size_t)row * FAN0 + e;
    atomicAdd(&acc_h[tgt0[idx]], sv * w0[idx]);
}

__global__ __launch_bounds__(256)
void k2_hidden_and_oscatter(const float* __restrict__ acc_h,
                            const float* __restrict__ w1,
                            const int*   __restrict__ tgt1,
                            float*       __restrict__ acc_o,   // ws+16384
                            float*       __restrict__ out)     // d_out
{
    __shared__ float lacc[256][24];              // lane-private accs, 24 KB
    const int tid = threadIdx.x;
    const int h = blockIdx.x * 256 + tid;

    #pragma unroll
    for (int o = 0; o < 24; ++o) lacc[tid][o] = 0.0f;

    const float ph0 = acc_h[h] * DECAY;          // potential after step 0 decay
    const bool  s_h = (ph0 >= THRESH);
    const float ph0p = s_h ? 0.0f : ph0;         // post-reset
    out[2 * OUT_SIZE + h] = ph0p;                // K4 scales by g later

    if (s_h) {                                   // scatter my w1 row, no atomics
        const float* wr = w1   + (size_t)h * FAN1;
        const int*   tr = tgt1 + (size_t)h * FAN1;
        #pragma unroll
        for (int k = 0; k < FAN1; ++k)
            lacc[tid][tr[k]] += wr[k];
    }
    __syncthreads();

    // tree-reduce 256 copies -> copy 0
    #pragma unroll
    for (int s = 128; s >= 1; s >>= 1) {
        if (tid < s) {
            #pragma unroll
            for (int o = 0; o < OUT_SIZE; ++o)
                lacc[tid][o] += lacc[tid + s][o];
        }
        __syncthreads();
    }
    if (tid < OUT_SIZE)
        atomicAdd(&acc_o[tid], lacc[0][tid]);    // 22 atomics per block
}

__global__ void k3_output_finalize(const float* __restrict__ acc_o,
                                   const int*   __restrict__ mt,
                                   float*       __restrict__ out,   // d_out
                                   float*       __restrict__ gp)    // ws+16406
{
    const int lane = threadIdx.x;                // 64 threads, 1 wave

    int T = mt[0];
    if (T < 0 || T > 1000000) {                  // tolerate f32-encoded scalar
        float tf = __int_as_float(T);
        T = (tf > 0.0f && tf < 1.0e6f) ? (int)tf : 0;
    }

    float ao = (lane < OUT_SIZE) ? acc_o[lane] : 0.0f;
    bool fired = (T >= 2) && (ao * DECAY >= THRESH);   // output fires at t=1
    unsigned long long b = __ballot(fired || lane >= OUT_SIZE);
    bool allfired = (b == ~0ULL);

    float g;                                     // decay^t_eff for pot_h
    if (T <= 0)      g = 0.0f;                   // init state: pot_h = 0
    else if (T == 1) g = 1.0f;                   // stop after step 0
    else {
        int t_eff = allfired ? 1 : (T - 1);
        g = __expf((float)(-t_eff) * (1.0f / 20.0f));   // = DECAY^t_eff
    }

    if (lane < OUT_SIZE) {
        out[lane]            = fired ? 1.0f : -1.0f;    // out_t
        out[OUT_SIZE + lane] = (T >= 2) ? ao * g : 0.0f; // pot_o = add_o*d^t_eff
    }
    if (lane == 0) gp[0] = g;
}

__global__ __launch_bounds__(256)
void k4_scale_pot_h(float* __restrict__ out, const float* __restrict__ gp)
{
    const float g = gp[0];
    const int h = blockIdx.x * 256 + threadIdx.x;
    out[2 * OUT_SIZE + h] *= g;
}

extern "C" void kernel_launch(void* const* d_in, const int* in_sizes, int n_in,
                              void* d_out, int out_size, void* d_ws, size_t ws_size,
                              hipStream_t stream) {
    const float* in_spk = (const float*)d_in[0];   // (40,)
    const float* w0     = (const float*)d_in[1];   // (40, 8192)
    const int*   tgt0   = (const int*)  d_in[2];   // (40, 8192)
    const float* w1     = (const float*)d_in[3];   // (16384, 11)
    const int*   tgt1   = (const int*)  d_in[4];   // (16384, 11)
    const int*   mt     = (const int*)  d_in[5];   // scalar max_timesteps
    float*       out    = (float*)d_out;           // [out_t 22 | pot_o 22 | pot_h 16384]

    float* acc_h = (float*)d_ws;                   // 16384
    float* acc_o = acc_h + HIDDEN;                 // 22
    float* gp    = acc_o + OUT_SIZE;               // 1

    hipMemsetAsync(d_ws, 0, (HIDDEN + OUT_SIZE + 1) * sizeof(float), stream);

    dim3 g1(FAN0 / 256, IN_SIZE);                  // 32 x 40 blocks
    k1_input_scatter<<<g1, 256, 0, stream>>>(in_spk, w0, tgt0, acc_h);
    k2_hidden_and_oscatter<<<HIDDEN / 256, 256, 0, stream>>>(acc_h, w1, tgt1, acc_o, out);
    k3_output_finalize<<<1, 64, 0, stream>>>(acc_o, mt, out, gp);
    k4_scale_pot_h<<<HIDDEN / 256, 256, 0, stream>>>(out, gp);
}